// Round 10
// baseline (2508.493 us; speedup 1.0000x reference)
//
#include <hip/hip_runtime.h>
#include <hip/hip_bf16.h>

#define B_ 8
#define S_ 4096
#define F_ 256
#define I_ 512
#define D_ 4
#define K_ 7
#define V_ 256
#define I3_ 1536
#define KE_ 3584           // 7*512 flattened causal-conv K
#define VR_ (S_ + 8)       // vbt rows: 6 zero-pad + 4096 + 2 slack

using bf16 = __hip_bfloat16;
typedef __bf16 bf16x8 __attribute__((ext_vector_type(8)));
typedef float  f32x4  __attribute__((ext_vector_type(4)));

#define LDS_PTR(p) ((__attribute__((address_space(3))) void*)(p))
#define GLB_PTR(p) ((const __attribute__((address_space(1))) void*)(p))

#define BARR_()  __builtin_amdgcn_s_barrier()
#define WLGKM_() asm volatile("s_waitcnt lgkmcnt(0)" ::: "memory")
#define WLGK8_() asm volatile("s_waitcnt lgkmcnt(8)" ::: "memory")
#define WVM0_()  asm volatile("s_waitcnt vmcnt(0)" ::: "memory")
#define WVM6_()  asm volatile("s_waitcnt vmcnt(6)" ::: "memory")
#define WVM8_()  asm volatile("s_waitcnt vmcnt(8)" ::: "memory")

// mish(x) = x*tanh(softplus(x)) = x*(u^2+2u)/(u^2+2u+2), u=e^x (exact closed form).
__device__ __forceinline__ float mishf(float x) {
    float u = expf(fminf(x, 30.0f));
    float t = u * (u + 2.0f);
    return x * (t / (t + 2.0f));
}

__device__ __forceinline__ float loadw(const void* p, size_t i, int isbf) {
    return isbf ? __bfloat162float(((const bf16*)p)[i]) : ((const float*)p)[i];
}

__device__ __forceinline__ __bf16 tobf(float x) {
    bf16 h = __float2bfloat16(x);
    return *(__bf16*)&h;
}

__device__ __forceinline__ float bf2f(__bf16 h) {
    unsigned short u = __builtin_bit_cast(unsigned short, h);
    unsigned int x = (unsigned int)u << 16;
    return __builtin_bit_cast(float, x);
}

// bf16 buffers of small weights never show bf16-exponent>=132 (|x|>=32);
// fp32 buffers read as uint16 do (random mantissa bits in low halves).
__global__ __launch_bounds__(256)
void detect_kernel(int* __restrict__ flag, const unsigned short* __restrict__ p)
{
    __shared__ int sh[256];
    int cnt = 0;
    for (int j = threadIdx.x; j < 16384; j += 256) {
        unsigned int e = (p[j] >> 7) & 0xffu;
        if (e >= 132u) cnt++;
    }
    sh[threadIdx.x] = cnt;
    __syncthreads();
    for (int s = 128; s > 0; s >>= 1) {
        if ((int)threadIdx.x < s) sh[threadIdx.x] += sh[threadIdx.x + s];
        __syncthreads();
    }
    if (threadIdx.x == 0) flag[0] = (sh[0] == 0) ? 1 : 0;   // 1 => bf16 inputs
}

__global__ __launch_bounds__(256)
void embed_kernel(float* __restrict__ x0, float* __restrict__ x1,
                  const int* __restrict__ inp, const void* __restrict__ emb,
                  const int* __restrict__ flag)
{
    const int isbf = flag[0];
    size_t idx = (size_t)blockIdx.x * 256 + threadIdx.x;   // over B*F*S
    int s = (int)(idx % S_);
    int f = (int)((idx / S_) % F_);
    int b = (int)(idx / ((size_t)S_ * F_));
    int tok = inp[b * S_ + s];
    x0[idx] = loadw(emb, (size_t)tok * (2 * F_) + f, isbf);
    x1[idx] = loadw(emb, (size_t)tok * (2 * F_) + F_ + f, isbf);
}

// zero the 6 pad rows of all P vbt slices (re-poisoned every call)
__global__ __launch_bounds__(256)
void zeropad_kernel(bf16* __restrict__ vbt, int nslice)
{
    int i = blockIdx.x * 256 + threadIdx.x;
    if (i < nslice * 6 * I_) {
        int z = i / (6 * I_), off = i % (6 * I_);
        vbt[(size_t)z * VR_ * I_ + off] = __float2bfloat16(0.0f);
    }
}

// merged per-depth weight prep (one dispatch instead of three):
//   job 0: wexp [o][k*512+c] <- w1 [o][c][k]   (I3*I indices)
//   job 1: wb0[i] <- (bf16)w0[o0w + i]         (I3*F indices)
//   job 2: wb2[i] <- (bf16)w2[o2w + i]         (F*I indices)
__global__ __launch_bounds__(256)
void wprep_kernel(bf16* __restrict__ wexp, bf16* __restrict__ wb0,
                  bf16* __restrict__ wb2, const void* __restrict__ w1,
                  const void* __restrict__ w0, const void* __restrict__ w2,
                  size_t o1w, size_t o0w, size_t o2w, const int* __restrict__ flag)
{
    const int isbf = flag[0];
    int idx = blockIdx.x * 256 + threadIdx.x;
    if (idx < I3_ * I_) {
        int c = idx & 511, o = idx >> 9;
        const size_t base = o1w + ((size_t)o * 512 + c) * 7;
        float vals[7];
        #pragma unroll
        for (int k = 0; k < 7; ++k) vals[k] = loadw(w1, base + k, isbf);
        #pragma unroll
        for (int k = 0; k < 7; ++k)
            wexp[(size_t)o * KE_ + (k << 9) + c] = __float2bfloat16(vals[k]);
    } else if (idx < I3_ * I_ + I3_ * F_) {
        int i = idx - I3_ * I_;
        wb0[i] = __float2bfloat16(loadw(w0, o0w + i, isbf));
    } else if (idx < I3_ * I_ + I3_ * F_ + F_ * I_) {
        int i = idx - I3_ * I_ - I3_ * F_;
        wb2[i] = __float2bfloat16(loadw(w2, o2w + i, isbf));
    }
}

// Inputs are PRE-MISHED by the gemm epilogue; SPLIT layout:
//   td [I][S] fp32  = depth plane (cumsum operand, kept fp32)
//   tb [2I][S] bf16 = scale plane (rows 0..I-1) then shift plane (rows I..)
// v[i,s] = cumsum_s(td[i,s])/(s+1) * tb[i,s] + tb[I+i,s]; bf16 output.
// grid (I_, P): blockIdx.y = z scratch slice
__global__ __launch_bounds__(256)
void scan_kernel(bf16* __restrict__ vout, const float* __restrict__ td,
                 const bf16* __restrict__ tb)
{
    const int z = blockIdx.y;
    const int i = blockIdx.x;
    td   += (size_t)z * I_ * S_;
    tb   += (size_t)z * 2 * I_ * S_;
    vout += (size_t)z * I_ * S_;
    const float* dp = td + (size_t)i * S_;
    const bf16* scp = tb + (size_t)i * S_;
    const bf16* shp = tb + (size_t)(I_ + i) * S_;
    bf16* op = vout + (size_t)i * S_;
    const int tid = threadIdx.x;
    const int base = tid * 16;

    float md[16];
    float lsum = 0.f;
    #pragma unroll
    for (int q = 0; q < 4; ++q) {
        float4 dv = *(const float4*)(dp + base + q * 4);
        #pragma unroll
        for (int j = 0; j < 4; ++j) {
            float m = (&dv.x)[j];
            md[q * 4 + j] = m;
            lsum += m;
        }
    }
    float ssum = lsum;
    #pragma unroll
    for (int off = 1; off < 64; off <<= 1) {
        float nv = __shfl_up(ssum, off, 64);
        if ((tid & 63) >= off) ssum += nv;
    }
    __shared__ float wtot[4];
    const int wid = tid >> 6, lane = tid & 63;
    if (lane == 63) wtot[wid] = ssum;
    __syncthreads();
    float excl = ssum - lsum;
    #pragma unroll
    for (int wq = 0; wq < 3; ++wq)
        if (wq < wid) excl += wtot[wq];

    bf16x8 scv0 = *(const bf16x8*)(const void*)(scp + base);
    bf16x8 scv1 = *(const bf16x8*)(const void*)(scp + base + 8);
    bf16x8 shv0 = *(const bf16x8*)(const void*)(shp + base);
    bf16x8 shv1 = *(const bf16x8*)(const void*)(shp + base + 8);

    float run = excl;
    bf16x8 o0v, o1v;
    #pragma unroll
    for (int e = 0; e < 16; ++e) {
        run += md[e];
        float sdiv = (float)(base + e + 1);
        float sc = bf2f((e < 8) ? scv0[e] : scv1[e - 8]);
        float sh = bf2f((e < 8) ? shv0[e] : shv1[e - 8]);
        float ov = run / sdiv * sc + sh;
        if (e < 8) o0v[e] = tobf(ov);
        else       o1v[e - 8] = tobf(ov);
    }
    *(bf16x8*)(void*)(op + base) = o0v;
    *(bf16x8*)(void*)(op + base + 8) = o1v;
}

// src fp32 [C][S_] (+z*szstr) -> dst bf16 [S_][C] (+z*dzstr); 64x64 LDS tile
__global__ __launch_bounds__(256)
void trans_kernel(bf16* __restrict__ dst, size_t dzstr,
                  const float* __restrict__ src, size_t szstr, int C)
{
    __shared__ __align__(16) bf16 lt[64][72];
    const int z = blockIdx.z;
    dst += (size_t)z * dzstr;
    src += (size_t)z * szstr;
    const int tid = threadIdx.x;
    const int s0 = blockIdx.x * 64;
    const int c0 = blockIdx.y * 64;
    #pragma unroll
    for (int p = 0; p < 4; ++p) {
        int c = p * 16 + (tid >> 4);
        int sc = (tid & 15) * 4;
        float4 f = *(const float4*)(src + (size_t)(c0 + c) * S_ + s0 + sc);
        #pragma unroll
        for (int j = 0; j < 4; ++j)
            lt[sc + j][c] = __float2bfloat16((&f.x)[j]);
    }
    __syncthreads();
    #pragma unroll
    for (int p = 0; p < 2; ++p) {
        int ch = p * 256 + tid;
        int r = ch >> 3, g = ch & 7;
        *(bf16x8*)(dst + (size_t)(s0 + r) * C + c0 + g * 8) =
            *(const bf16x8*)&lt[r][g * 8];
    }
}

// src bf16 [C][S_] (+z*szstr) -> dst bf16 [S_][C] (+z*dzstr); 64x64 LDS tile
__global__ __launch_bounds__(256)
void transb_kernel(bf16* __restrict__ dst, size_t dzstr,
                   const bf16* __restrict__ src, size_t szstr, int C)
{
    __shared__ __align__(16) bf16 lt[64][72];
    const int z = blockIdx.z;
    dst += (size_t)z * dzstr;
    src += (size_t)z * szstr;
    const int tid = threadIdx.x;
    const int s0 = blockIdx.x * 64;
    const int c0 = blockIdx.y * 64;
    #pragma unroll
    for (int p = 0; p < 2; ++p) {
        int c = p * 32 + (tid >> 3);
        int sc = (tid & 7) * 8;
        bf16x8 v = *(const bf16x8*)(src + (size_t)(c0 + c) * S_ + s0 + sc);
        #pragma unroll
        for (int j = 0; j < 8; ++j)
            *(__bf16*)&lt[sc + j][c] = v[j];
    }
    __syncthreads();
    #pragma unroll
    for (int p = 0; p < 2; ++p) {
        int ch = p * 256 + tid;
        int r = ch >> 3, g = ch & 7;
        *(bf16x8*)(dst + (size_t)(s0 + r) * C + c0 + g * 8) =
            *(const bf16x8*)&lt[r][g * 8];
    }
}

// ---------------------------------------------------------------------------
// 192(o) x 256(s) tile GEMM (P<=4 fallback), double-buffered LDS (112 KiB),
// two phases / two barriers per K-tile (R7-verified). Grid 16 x 8 x P.
// Epilogue: mish, SPLIT write (og<I -> outd fp32; og>=I -> outb bf16).
// ---------------------------------------------------------------------------
__global__ __launch_bounds__(512, 1)
void gemm192_kernel(float* __restrict__ outd, bf16* __restrict__ outb,
                    const bf16* __restrict__ Aw, int lda,
                    const bf16* __restrict__ Bm, size_t bzstr, int ldb,
                    int Kdim, int conv)
{
    __shared__ __align__(16) bf16 la[2][192][64];   // 48 KiB
    __shared__ __align__(16) bf16 lb[2][256][64];   // 64 KiB  (112 total)
    const int tid = threadIdx.x;
    const int s0 = blockIdx.x * 256;
    const int o0 = blockIdx.y * 192;
    const int z  = blockIdx.z;
    outd += (size_t)z * I_ * S_;
    outb += (size_t)z * 2 * I_ * S_;
    Bm   += (size_t)z * bzstr;
    const int wv = tid >> 6, lane = tid & 63;
    const int wr = wv >> 2, wc = wv & 3;            // 2(M) x 4(N) waves
    const int l16 = lane & 15, q = lane >> 4;
    const int srow = lane >> 3;
    const int schunk = (lane & 7) ^ srow;
    const int nKt = Kdim >> 6;

    f32x4 acc[6][4];
    #pragma unroll
    for (int i = 0; i < 6; ++i)
        #pragma unroll
        for (int j = 0; j < 4; ++j)
            #pragma unroll
            for (int r = 0; r < 4; ++r) acc[i][j][r] = 0.f;

#define STAGE_A3(buf, kt) do {                                                \
    const bf16* gpA_ = Aw + (size_t)(o0 + wv * 8 + srow) * lda                \
                          + ((kt) << 6) + (schunk << 3);                      \
    __builtin_amdgcn_global_load_lds(GLB_PTR(gpA_),                           \
        LDS_PTR(&la[buf][wv * 8][0]), 16, 0, 0);                              \
    __builtin_amdgcn_global_load_lds(GLB_PTR(gpA_ + (size_t)64 * lda),        \
        LDS_PTR(&la[buf][64 + wv * 8][0]), 16, 0, 0);                         \
    __builtin_amdgcn_global_load_lds(GLB_PTR(gpA_ + (size_t)128 * lda),       \
        LDS_PTR(&la[buf][128 + wv * 8][0]), 16, 0, 0);                        \
} while (0)

#define STAGE_BL(buf, l, ro, bk) do {                                         \
    const bf16* gpB_ = Bm + (size_t)(s0 + (l) * 64 + wv * 8 + srow + (ro)) * ldb \
                          + (bk) + (schunk << 3);                             \
    __builtin_amdgcn_global_load_lds(GLB_PTR(gpB_),                           \
        LDS_PTR(&lb[buf][(l) * 64 + wv * 8][0]), 16, 0, 0);                   \
} while (0)

#define LDAF6(buf, kk) do {                                                   \
    _Pragma("unroll") for (int i2 = 0; i2 < 6; ++i2) {                        \
        int r_ = wr * 96 + i2 * 16 + l16;                                     \
        af[i2] = *(const bf16x8*)&la[buf][r_][(((kk) * 4 + q) ^ (r_ & 7)) << 3]; \
    }                                                                         \
} while (0)

#define LDBF4(buf, kk) do {                                                   \
    _Pragma("unroll") for (int j2 = 0; j2 < 4; ++j2) {                        \
        int r_ = wc * 64 + j2 * 16 + l16;                                     \
        bfr[j2] = *(const bf16x8*)&lb[buf][r_][(((kk) * 4 + q) ^ (r_ & 7)) << 3]; \
    }                                                                         \
} while (0)

#define MFMA24() do {                                                         \
    __builtin_amdgcn_s_setprio(1);                                            \
    _Pragma("unroll") for (int i2 = 0; i2 < 6; ++i2)                          \
    _Pragma("unroll") for (int j2 = 0; j2 < 4; ++j2)                          \
        acc[i2][j2] = __builtin_amdgcn_mfma_f32_16x16x32_bf16(                \
            af[i2], bfr[j2], acc[i2][j2], 0, 0, 0);                           \
    __builtin_amdgcn_s_setprio(0);                                            \
} while (0)

    STAGE_A3(0, 0);
    STAGE_BL(0, 0, 0, 0); STAGE_BL(0, 1, 0, 0);
    STAGE_BL(0, 2, 0, 0); STAGE_BL(0, 3, 0, 0);
    WVM0_();
    BARR_();

    bf16x8 af[6], bfr[4];
    for (int t = 0; t < nKt; ++t) {
        const int c = t & 1, n = c ^ 1;
        const bool st = (t + 1) < nKt;
        int ro1 = 0, bk1 = (t + 1) << 6;
        if (conv) { ro1 = bk1 >> 9; bk1 &= 511; }
        LDAF6(c, 0); LDBF4(c, 0);
        if (st) {
            STAGE_A3(n, t + 1);
            STAGE_BL(n, 0, ro1, bk1); STAGE_BL(n, 1, ro1, bk1);
            STAGE_BL(n, 2, ro1, bk1); STAGE_BL(n, 3, ro1, bk1);
        }
        BARR_(); WLGKM_();
        MFMA24();
        LDAF6(c, 1); LDBF4(c, 1);
        if (st) WVM0_();
        BARR_(); WLGKM_();
        MFMA24();
    }

    // C/D: col(lane&15)=s, row(q*4+reg)=o   [verified convention]
    #pragma unroll
    for (int i = 0; i < 6; ++i)
        #pragma unroll
        for (int j = 0; j < 4; ++j) {
            int sg = s0 + wc * 64 + j * 16 + l16;
            #pragma unroll
            for (int r = 0; r < 4; ++r) {
                int og = o0 + wr * 96 + i * 16 + q * 4 + r;
                float v = mishf(acc[i][j][r]);
                if (og < I_) outd[(size_t)og * S_ + sg] = v;
                else outb[(size_t)(og - I_) * S_ + sg] = __float2bfloat16(v);
            }
        }
#undef STAGE_A3
#undef STAGE_BL
#undef LDAF6
#undef LDBF4
#undef MFMA24
}

// ---------------------------------------------------------------------------
// 256 x 256 tile GEMM (P=8 path), m201-faithful 8-PHASE schedule.
// Grid 16 x 6 x 8 = 768 = exactly 3 rounds over 256 CUs (tail-free).
// 8 waves (2M x 4N); per-wave 128o x 64s; acc[8][4]; 128 KiB LDS (2 buf).
// Iteration = 2 K-tiles: t0 (buf0, ph1-4) + t0+1 (buf1, ph5-8).
// Phase = {ds_read quadrant frags || 1 half-tile stage (2 gload_lds) ||
//          BARR || lgkm(0) || setprio 16 MFMA || BARR}; MFMA quadrant order
// (0,0)(0,1)(1,1)(1,0) so each frag set is read once and held in regs.
// Stage halves are the INTERLEAVED row sets matching phase-local last reads:
//   Ah = rows {h*64+[0,64)} u {128+h*64+[0,64)}, Bh = {blk*64+h*32+[0,32)}.
// Stage slots: ph2:Ah0(t+2) ph3:Bh0(t+2) ph4:Bh1(t+2) ph5:Ah1(t+2)
//              ph6:Ah0(t+3) ph7:Bh0(t+3) ph8:Bh1(t+3) ph1':Ah1(t+3).
// WAR: each restage is >=1 trailing barrier after its region's last read
//  (Ah0 read ph1, Bh0 ph1, Bh1 ph2, Ah1 ph3; buf1 shifted +4). RAW/counted
// vmcnt: per-wave at ph4/ph8 outstanding = 14, the 8 OLDEST are exactly the
// next-needed tile -> vmcnt(6) drains them, leaves 6 flying (never 0 in
// steady state — T4). Prologue: 16 loads, vmcnt(8) lands tile0 only.
// Tails: st2/st3 guards; waits fall back to vmcnt(0).
// Epilogue: mish + split-plane write (og<I fp32 depth; else bf16).
// ---------------------------------------------------------------------------
__global__ __launch_bounds__(512, 1)
void gemm256_kernel(float* __restrict__ outd, bf16* __restrict__ outb,
                    const bf16* __restrict__ Aw, int lda,
                    const bf16* __restrict__ Bm, size_t bzstr, int ldb,
                    int Kdim, int conv)
{
    __shared__ __align__(16) bf16 la[2][256][64];   // 64 KiB
    __shared__ __align__(16) bf16 lb[2][256][64];   // 64 KiB (128 total)
    const int tid = threadIdx.x;
    const int s0 = blockIdx.x * 256;
    const int o0 = blockIdx.y * 256;
    const int z  = blockIdx.z;
    outd += (size_t)z * I_ * S_;
    outb += (size_t)z * 2 * I_ * S_;
    Bm   += (size_t)z * bzstr;
    const int wv = tid >> 6, lane = tid & 63;
    const int wr = wv >> 2, wc = wv & 3;            // 2(M) x 4(N) waves
    const int l16 = lane & 15, q = lane >> 4;
    const int srow = lane >> 3;
    const int schunk = (lane & 7) ^ srow;
    const int nKt = Kdim >> 6;                      // even, >=2

    f32x4 acc[8][4];
    #pragma unroll
    for (int i = 0; i < 8; ++i)
        #pragma unroll
        for (int j = 0; j < 4; ++j)
            #pragma unroll
            for (int r = 0; r < 4; ++r) acc[i][j][r] = 0.f;

#define STAGE_AH(buf, h, kt) do {                                             \
    const bf16* gpA_ = Aw + (size_t)(o0 + (h) * 64 + wv * 8 + srow) * lda     \
                          + ((kt) << 6) + (schunk << 3);                      \
    __builtin_amdgcn_global_load_lds(GLB_PTR(gpA_),                           \
        LDS_PTR(&la[buf][(h) * 64 + wv * 8][0]), 16, 0, 0);                   \
    __builtin_amdgcn_global_load_lds(GLB_PTR(gpA_ + (size_t)128 * lda),       \
        LDS_PTR(&la[buf][128 + (h) * 64 + wv * 8][0]), 16, 0, 0);             \
} while (0)

#define STAGE_BH(buf, h, ro, bk) do {                                         \
    const int rb_ = (h) * 32 + (wv >> 2) * 64 + (wv & 3) * 8;                 \
    const bf16* gpB_ = Bm + (size_t)(s0 + rb_ + srow + (ro)) * ldb            \
                          + (bk) + (schunk << 3);                             \
    __builtin_amdgcn_global_load_lds(GLB_PTR(gpB_),                           \
        LDS_PTR(&lb[buf][rb_][0]), 16, 0, 0);                                 \
    __builtin_amdgcn_global_load_lds(GLB_PTR(gpB_ + (size_t)128 * ldb),       \
        LDS_PTR(&lb[buf][128 + rb_][0]), 16, 0, 0);                           \
} while (0)

#define LDAQ(buf, qa) do {                                                    \
    _Pragma("unroll") for (int i2 = 0; i2 < 4; ++i2)                          \
    _Pragma("unroll") for (int kk = 0; kk < 2; ++kk) {                        \
        int r_ = wr * 128 + (qa) * 64 + i2 * 16 + l16;                        \
        af[i2 * 2 + kk] =                                                     \
            *(const bf16x8*)&la[buf][r_][((kk * 4 + q) ^ (r_ & 7)) << 3];     \
    }                                                                         \
} while (0)

#define LDBQ(dst, buf, qb) do {                                               \
    _Pragma("unroll") for (int j2 = 0; j2 < 2; ++j2)                          \
    _Pragma("unroll") for (int kk = 0; kk < 2; ++kk) {                        \
        int r_ = wc * 64 + (qb) * 32 + j2 * 16 + l16;                         \
        dst[j2 * 2 + kk] =                                                    \
            *(const bf16x8*)&lb[buf][r_][((kk * 4 + q) ^ (r_ & 7)) << 3];     \
    }                                                                         \
} while (0)

#define MFMAQ(qa, qb, bfx) do {                                               \
    __builtin_amdgcn_s_setprio(1);                                            \
    _Pragma("unroll") for (int kk = 0; kk < 2; ++kk)                          \
    _Pragma("unroll") for (int i2 = 0; i2 < 4; ++i2)                          \
    _Pragma("unroll") for (int j2 = 0; j2 < 2; ++j2)                          \
        acc[(qa) * 4 + i2][(qb) * 2 + j2] =                                   \
            __builtin_amdgcn_mfma_f32_16x16x32_bf16(                          \
                af[i2 * 2 + kk], bfx[j2 * 2 + kk],                            \
                acc[(qa) * 4 + i2][(qb) * 2 + j2], 0, 0, 0);                  \
    __builtin_amdgcn_s_setprio(0);                                            \
} while (0)

    // prologue: tile0 -> buf0 (8 loads), tile1 -> buf1 (8 loads); land tile0.
    STAGE_AH(0, 0, 0); STAGE_AH(0, 1, 0);
    STAGE_BH(0, 0, 0, 0); STAGE_BH(0, 1, 0, 0);
    STAGE_AH(1, 0, 1); STAGE_AH(1, 1, 1);
    STAGE_BH(1, 0, 0, 64); STAGE_BH(1, 1, 0, 64);   // k=64: ro=0,bk=64 (conv too)
    WVM8_();
    BARR_();

    bf16x8 af[8], bf0[4], bf1[4];
    for (int t0 = 0; t0 < nKt; t0 += 2) {
        const bool st2 = (t0 + 2) < nKt;
        const bool st3 = (t0 + 3) < nKt;
        int ro2 = 0, bk2 = (t0 + 2) << 6;
        int ro3 = 0, bk3 = (t0 + 3) << 6;
        if (conv) { ro2 = bk2 >> 9; bk2 &= 511; ro3 = bk3 >> 9; bk3 &= 511; }
        // ---- ph1 (0,0) on buf0: 12 reads; stage Ah1(t0+1)->buf1
        LDAQ(0, 0); LDBQ(bf0, 0, 0);
        if (t0 > 0) STAGE_AH(1, 1, t0 + 1);
        WLGK8_(); BARR_(); WLGKM_();
        MFMAQ(0, 0, bf0);
        BARR_();
        // ---- ph2 (0,1): 4 reads; stage Ah0(t0+2)->buf0
        LDBQ(bf1, 0, 1);
        if (st2) STAGE_AH(0, 0, t0 + 2);
        BARR_(); WLGKM_();
        MFMAQ(0, 1, bf1);
        BARR_();
        // ---- ph3 (1,1): 8 reads; stage Bh0(t0+2)->buf0
        LDAQ(0, 1);
        if (st2) STAGE_BH(0, 0, ro2, bk2);
        BARR_(); WLGKM_();
        MFMAQ(1, 1, bf1);
        BARR_();
        // ---- ph4 (1,0): 0 reads; stage Bh1(t0+2)->buf0; counted wait
        if (st2) STAGE_BH(0, 1, ro2, bk2);
        BARR_();
        MFMAQ(1, 0, bf0);
        if (st2) { WVM6_(); } else { WVM0_(); }     // tile t0+1 fully landed
        BARR_();
        // ---- ph5 (0,0) on buf1: 12 reads; stage Ah1(t0+2)->buf0
        LDAQ(1, 0); LDBQ(bf0, 1, 0);
        if (st2) STAGE_AH(0, 1, t0 + 2);
        WLGK8_(); BARR_(); WLGKM_();
        MFMAQ(0, 0, bf0);
        BARR_();
        // ---- ph6 (0,1): 4 reads; stage Ah0(t0+3)->buf1
        LDBQ(bf1, 1, 1);
        if (st3) STAGE_AH(1, 0, t0 + 3);
        BARR_(); WLGKM_();
        MFMAQ(0, 1, bf1);
        BARR_();
        // ---- ph7 (1,1): 8 reads; stage Bh0(t0+3)->buf1
        LDAQ(1, 1);
        if (st3) STAGE_BH(1, 0, ro3, bk3);
        BARR_(); WLGKM_();
        MFMAQ(1, 1, bf1);
        BARR_();
        // ---- ph8 (1,0): 0 reads; stage Bh1(t0+3)->buf1; counted wait
        if (st3) STAGE_BH(1, 1, ro3, bk3);
        BARR_();
        MFMAQ(1, 0, bf0);
        if (st3) { WVM6_(); } else { WVM0_(); }     // tile t0+2 fully landed
        BARR_();
    }

    // C/D: col(lane&15)=s, row(q*4+reg)=o   [verified convention]
    #pragma unroll
    for (int i = 0; i < 8; ++i)
        #pragma unroll
        for (int j = 0; j < 4; ++j) {
            int sg = s0 + wc * 64 + j * 16 + l16;
            #pragma unroll
            for (int r = 0; r < 4; ++r) {
                int og = o0 + wr * 128 + i * 16 + q * 4 + r;
                float v = mishf(acc[i][j][r]);
                if (og < I_) outd[(size_t)og * S_ + sg] = v;
                else outb[(size_t)(og - I_) * S_ + sg] = __float2bfloat16(v);
            }
        }
#undef STAGE_AH
#undef STAGE_BH
#undef LDAQ
#undef LDBQ
#undef MFMAQ
}

// 128x128 GEMM for the small w2 conv (M=256) + accumulate.
// Double-buffered 2-barrier schedule. Grid = 32 x 2 x P.
__global__ __launch_bounds__(256)
void gemm128_kernel(float* __restrict__ out, size_t ozstr,
                    const bf16* __restrict__ Aw, int lda,
                    const bf16* __restrict__ Bm, size_t bzstr, int ldb,
                    int Kdim, int conv, int addres)
{
    __shared__ __align__(16) bf16 la[2][128][64];   // 32 KiB
    __shared__ __align__(16) bf16 lb[2][128][64];   // 32 KiB (64 total)
    const int tid = threadIdx.x;
    const int s0 = blockIdx.x * 128;
    const int o0 = blockIdx.y * 128;
    const int z  = blockIdx.z;
    out += (size_t)z * ozstr;
    Bm  += (size_t)z * bzstr;
    const int wv = tid >> 6, lane = tid & 63;
    const int wo = wv & 1, wsv = wv >> 1;
    const int l16 = lane & 15, q = lane >> 4;
    const int lrow = lane >> 3, lslot = lane & 7;
    const int nKt = Kdim >> 6;

    f32x4 acc[4][4];
    #pragma unroll
    for (int i = 0; i < 4; ++i)
        #pragma unroll
        for (int j = 0; j < 4; ++j)
            #pragma unroll
            for (int r = 0; r < 4; ++r) acc[i][j][r] = 0.f;

#define G128_STAGE(buf, kt) do {                                              \
    int k0_ = (kt) << 6; int roff_ = 0, bk_ = k0_;                            \
    if (conv) { roff_ = k0_ >> 9; bk_ = k0_ & 511; }                          \
    _Pragma("unroll") for (int t_ = 0; t_ < 4; ++t_) {                        \
        int rbase = wv * 32 + t_ * 8;                                         \
        int row = rbase + lrow;                                               \
        int chunk = lslot ^ (row & 7);                                        \
        __builtin_amdgcn_global_load_lds(                                     \
            GLB_PTR(Aw + (size_t)(o0 + row) * lda + k0_ + chunk * 8),         \
            LDS_PTR(&la[buf][rbase][0]), 16, 0, 0);                           \
        __builtin_amdgcn_global_load_lds(                                     \
            GLB_PTR(Bm + (size_t)(s0 + row + roff_) * ldb + bk_ + chunk * 8), \
            LDS_PTR(&lb[buf][rbase][0]), 16, 0, 0);                           \
    }                                                                         \
} while (0)

#define G128_RD(buf, kk) do {                                                 \
    _Pragma("unroll") for (int i = 0; i < 4; ++i) {                           \
        int r = wo * 64 + i * 16 + l16;                                       \
        af[i] = *(const bf16x8*)&la[buf][r][(((kk) * 4 + q) ^ (r & 7)) * 8];  \
    }                                                                         \
    _Pragma("unroll") for (int j = 0; j < 4; ++j) {                           \
        int r = wsv * 64 + j * 16 + l16;                                      \
        bfr[j] = *(const bf16x8*)&lb[buf][r][(((kk) * 4 + q) ^ (r & 7)) * 8]; \
    }                                                                         \
} while (0)

#define G128_MFMA16() do {                                                    \
    __builtin_amdgcn_s_setprio(1);                                            \
    _Pragma("unroll") for (int i = 0; i < 4; ++i)                             \
    _Pragma("unroll") for (int j = 0; j < 4; ++j)                             \
        acc[i][j] = __builtin_amdgcn_mfma_f32_16x16x32_bf16(                  \
            af[i], bfr[j], acc[i][j], 0, 0, 0);                               \
    __builtin_amdgcn_s_setprio(0);                                            \
} while (0)

    G128_STAGE(0, 0);
    WVM0_();
    BARR_();

    bf16x8 af[4], bfr[4];
    for (int t = 0; t < nKt; ++t) {
        const int c = t & 1, n = c ^ 1;
        const bool st = (t + 1) < nKt;
        G128_RD(c, 0);
        if (st) G128_STAGE(n, t + 1);
        BARR_(); WLGKM_();
        G128_MFMA16();
        G128_RD(c, 1);
        if (st) WVM0_();
        BARR_(); WLGKM_();
        G128_MFMA16();
    }

    #pragma unroll
    for (int i = 0; i < 4; ++i)
        #pragma unroll
        for (int j = 0; j < 4; ++j) {
            int sg = s0 + wsv * 64 + j * 16 + l16;
            #pragma unroll
            for (int r = 0; r < 4; ++r) {
                int og = o0 + wo * 64 + i * 16 + q * 4 + r;
                float v = acc[i][j][r];
                if (addres) v += out[(size_t)og * S_ + sg];
                out[(size_t)og * S_ + sg] = v;
            }
        }
#undef G128_STAGE
#undef G128_RD
#undef G128_MFMA16
}

__global__ __launch_bounds__(256)
void final_kernel(void* __restrict__ out, const float* __restrict__ x0,
                  const float* __restrict__ x1, const void* __restrict__ ow,
                  const void* __restrict__ ob, const int* __restrict__ flag)
{
    __shared__ float wl[16][68];
    __shared__ float xl[16][68];
    const int isbf = flag[0];
    const int tid = threadIdx.x;
    const int tx = tid & 15, ty = tid >> 4;
    const int s0 = blockIdx.x * 64;
    const int o0 = blockIdx.y * 64;
    const int b  = blockIdx.z;
    float acc[4][4] = {};
    for (int c0 = 0; c0 < 2 * F_; c0 += 16) {
        if (isbf) {
            #pragma unroll
            for (int e = tid; e < 1024; e += 256) {
                int k = e & 15, o = e >> 4;
                wl[k][o] = __bfloat162float(((const bf16*)ow)[(size_t)(o0 + o) * (2 * F_) + (c0 + k)]);
            }
        } else {
            #pragma unroll
            for (int e = tid; e < 1024; e += 256) {
                int k = e & 15, o = e >> 4;
                wl[k][o] = ((const float*)ow)[(size_t)(o0 + o) * (2 * F_) + (c0 + k)];
            }
        }
        {
            int r = tid >> 4;
            int qq = (tid & 15) * 4;
            int cr = c0 + r;
            const float* src = (cr < F_) ? (x0 + ((size_t)b * F_ + cr) * S_)
                                         : (x1 + ((size_t)b * F_ + (cr - F_)) * S_);
            *(float4*)&xl[r][qq] = *(const float4*)(src + s0 + qq);
        }
        __syncthreads();
        #pragma unroll
        for (int k = 0; k < 16; ++k) {
            float4 av = *(const float4*)&wl[k][ty * 4];
            float4 bv = *(const float4*)&xl[k][tx * 4];
            #pragma unroll
            for (int i = 0; i < 4; ++i)
                #pragma unroll
                for (int j = 0; j < 4; ++j)
                    acc[i][j] += (&av.x)[i] * (&bv.x)[j];
        }
        __syncthreads();
    }
    #pragma unroll
    for (int i = 0; i < 4; ++i) {
        int o = o0 + ty * 4 + i;
        float bias = loadw(ob, o, isbf);
        size_t outoff = ((size_t)b * V_ + o) * S_ + s0 + tx * 4;
        if (isbf) {
            bf16* po = (bf16*)out + outoff;
            #pragma unroll
            for (int j = 0; j < 4; ++j)
                po[j] = __float2bfloat16(acc[i][j] + bias);
        } else {
            float* po = (float*)out + outoff;
            *(float4*)po = make_float4(acc[i][0] + bias, acc[i][1] + bias,
                                       acc[i][2] + bias, acc[i][3] + bias);
        }
    }
}

extern "C" void kernel_launch(void* const* d_in, const int* in_sizes, int n_in,
                              void* d_out, int out_size, void* d_ws, size_t ws_size,
                              hipStream_t stream)
{
    const int*  inp  = (const int*)d_in[0];
    const void* emb  = d_in[1];
    const void* w0   = d_in[2];
    const void* w1   = d_in[3];
    const void* w2   = d_in[4];
    const void* outw = d_in[5];
    const void* outb = d_in[6];

    const size_t NX = (size_t)B_ * F_ * S_;
    const size_t NIS = (size_t)I_ * S_;       // one I x S plane
    const size_t VSTR = (size_t)VR_ * I_;     // vbt z-stride (elements)

    // P = batch slices per dispatch. Layout:
    //   Td fp32 [P][I][S] + Tb bf16 [P][2I][S] + Vv bf16 [P][I][S]
    auto need = [&](int p) -> size_t {
        return 256 + 8 * NX
             + (size_t)4 * p * NIS            // Td
             + (size_t)4 * p * NIS            // Tb (2I*S bf16 = 4*NIS bytes)
             + (size_t)2 * p * NIS            // Vv
             + 2 * ((size_t)I3_ * KE_ + (size_t)p * VSTR + (size_t)p * S_ * F_
                    + (size_t)I3_ * F_ + (size_t)F_ * I_);
    };
    int P = 2;
    if (ws_size >= need(8)) P = 8;
    else if (ws_size >= need(4)) P = 4;

    int*   flag = (int*)d_ws;
    float* A  = (float*)d_ws + 64;
    float* Bb = A + NX;
    float* Td = Bb + NX;                       // P slices fp32 (depth plane)
    bf16*  Tb = (bf16*)(Td + (size_t)P * NIS); // P slices bf16 (scale+shift)
    bf16*  Vv = Tb + (size_t)P * 2 * NIS;      // P slices bf16
    bf16*  wexp = Vv + (size_t)P * NIS;
    bf16*  vbt  = wexp + (size_t)I3_ * KE_;    // P slices, 6-row zero pad each
    bf16*  xbt  = vbt + (size_t)P * VSTR;      // P slices
    bf16*  wb0  = xbt + (size_t)P * S_ * F_;
    bf16*  wb2  = wb0 + (size_t)I3_ * F_;

    detect_kernel<<<1, 256, 0, stream>>>(flag, (const unsigned short*)emb);
    embed_kernel<<<dim3((unsigned)(NX / 256)), 256, 0, stream>>>(A, Bb, inp, emb, flag);
    zeropad_kernel<<<dim3((P * 6 * I_ + 255) / 256), 256, 0, stream>>>(vbt, P);

    const unsigned WPREP_GRID = (I3_ * I_ + I3_ * F_ + F_ * I_ + 255) / 256;
    int swap = 0;
    for (int d = 0; d < D_; ++d) {
        wprep_kernel<<<dim3(WPREP_GRID), 256, 0, stream>>>(
            wexp, wb0, wb2, w1, w0, w2,
            (size_t)d * I3_ * I_ * K_, (size_t)d * I3_ * F_,
            (size_t)d * F_ * I_, flag);
        for (int bp = 0; bp < B_ / P; ++bp) {
            float* x0 = (swap ? Bb : A) + (size_t)(P * bp) * F_ * S_;
            float* x1 = (swap ? A : Bb) + (size_t)(P * bp) * F_ * S_;
            // xbt[z] = x1(b)^T bf16
            trans_kernel<<<dim3(S_ / 64, F_ / 64, P), 256, 0, stream>>>(
                xbt, (size_t)S_ * F_, x1, (size_t)F_ * S_, F_);
            // Td/Tb = mish(wb0 @ xbt[z]) split-plane
            if (P == 8)
                gemm256_kernel<<<dim3(S_ / 256, I3_ / 256, 8), 512, 0, stream>>>(
                    Td, Tb, wb0, F_, xbt, (size_t)S_ * F_, F_, F_, 0);
            else
                gemm192_kernel<<<dim3(S_ / 256, I3_ / 192, P), 512, 0, stream>>>(
                    Td, Tb, wb0, F_, xbt, (size_t)S_ * F_, F_, F_, 0);
            scan_kernel<<<dim3(I_, P), 256, 0, stream>>>(Vv, Td, Tb);
            // vbt[z] rows 6.. = Vv[z]^T (pad rows 0..5 stay zero)
            transb_kernel<<<dim3(S_ / 64, I_ / 64, P), 256, 0, stream>>>(
                vbt + 6 * I_, VSTR, Vv, NIS, I_);
            // Td/Tb = mish(causal conv as flattened-K GEMM)
            if (P == 8)
                gemm256_kernel<<<dim3(S_ / 256, I3_ / 256, 8), 512, 0, stream>>>(
                    Td, Tb, wexp, KE_, vbt, VSTR, I_, KE_, 1);
            else
                gemm192_kernel<<<dim3(S_ / 256, I3_ / 192, P), 512, 0, stream>>>(
                    Td, Tb, wexp, KE_, vbt, VSTR, I_, KE_, 1);
            scan_kernel<<<dim3(I_, P), 256, 0, stream>>>(Vv, Td, Tb);
            transb_kernel<<<dim3(S_ / 64, I_ / 64, P), 256, 0, stream>>>(
                vbt + 6 * I_, VSTR, Vv, NIS, I_);
            // x0(b) += wb2 @ v[z]   (128-tile 2-barrier, grid 32*2*P)
            gemm128_kernel<<<dim3(S_ / 128, F_ / 128, P), 256, 0, stream>>>(
                x0, (size_t)F_ * S_, wb2, I_, vbt + 6 * I_, VSTR, I_, I_, 0, 1);
        }
        swap ^= 1;
    }
    final_kernel<<<dim3(S_ / 64, V_ / 64, B_), 256, 0, stream>>>(d_out, A, Bb, outw, outb, flag);
    (void)in_sizes; (void)n_in; (void)out_size;
}